// Round 6
// baseline (257.791 us; speedup 1.0000x reference)
//
#include <hip/hip_runtime.h>

// ---------- kernel 1: bucket tokens by partition ----------
__global__ void bucket_k(const int* __restrict__ x, const int* __restrict__ parts,
                         int* __restrict__ counts, int* __restrict__ buckets, int NT) {
    __shared__ int lcount[8];
    __shared__ int lbase[8];
    const int tid = threadIdx.x;
    if (tid < 8) lcount[tid] = 0;
    __syncthreads();

    const int i = blockIdx.x * blockDim.x + tid;
    int p = 0, lpos = 0;
    const bool valid = (i < NT);
    if (valid) {
        p = parts[x[i]];
        lpos = atomicAdd(&lcount[p], 1);
    }
    __syncthreads();
    if (tid < 8)
        lbase[tid] = lcount[tid] ? atomicAdd(&counts[tid], lcount[tid]) : 0;
    __syncthreads();
    if (valid)
        buckets[(size_t)p * NT + lbase[p] + lpos] = i;
}

// ---------- kernel 2: grouped GEMM per partition (fp32) ----------
// R5 PROBE: kernel body byte-identical to R4. Launched 5x (idempotent) to
// measure T_gemm = (total - 168.0)/4 and calibrate the harness floor.
#define TT 64     // tokens per tile
#define XB 40     // token-tile grid (covers n_p <= 2560; loop beyond)

__global__ __launch_bounds__(256)
void fge_gemm(const int* __restrict__ x,
              const float* __restrict__ emb,
              const float* __restrict__ weight,
              const int* __restrict__ counts,
              const int* __restrict__ buckets,
              float* __restrict__ out, int NT) {
    const int p = blockIdx.z;
    const int n = counts[p];
    if ((int)(blockIdx.x * TT) >= n) return;
    const int z0  = blockIdx.y * 64;
    const int K   = 256 >> p;                 // true active dim
    const int KP  = (K < 16) ? 16 : K;        // zero-padded K (keeps b128 strides)
    const int KC  = (KP < 64) ? KP : 64;      // K chunk size (16/32/64)
    const int nch = KP / KC;
    const int tid = threadIdx.x;

    __shared__ __align__(16) float e_lds[TT * 64];   // [t][k], row stride KC
    __shared__ __align__(16) float w_lds[64 * 64];   // [k][z] swizzled
    __shared__ int vrow[TT];
    __shared__ int oidx[TT];

    const int tg  = tid >> 4;        // token group: owns tokens tg*4 .. +3
    const int zg4 = (tid & 15) * 4;  // z offset: owns z0+zg4 .. +3

    for (int t0 = blockIdx.x * TT; t0 < n; t0 += XB * TT) {
        const int ntile = min(TT, n - t0);

        __syncthreads();
        if (tid < TT) {
            int idx = 0, row = 0;
            if (tid < ntile) {
                idx = buckets[(size_t)p * NT + t0 + tid];
                row = x[idx];
            }
            oidx[tid] = idx;
            vrow[tid] = row;
        }
        __syncthreads();

        float acc[4][4] = {};

        for (int ch = 0; ch < nch; ++ch) {
            const int kbase = ch * KC;
            const int lpr   = KC >> 2;

            // ---- stage E [TT][KC] row-major, coalesced ----
            {
                const int passes = (TT * lpr) >> 8;
                for (int ps = 0; ps < passes; ++ps) {
                    const int idx = ps * 256 + tid;
                    const int row = idx / lpr;
                    const int c4  = (idx - row * lpr) * 4;
                    const float4 v = *(const float4*)(emb + (size_t)vrow[row] * 256 + kbase + c4);
                    float4 o;
                    o.x = (kbase + c4 + 0 < K) ? v.x : 0.f;
                    o.y = (kbase + c4 + 1 < K) ? v.y : 0.f;
                    o.z = (kbase + c4 + 2 < K) ? v.z : 0.f;
                    o.w = (kbase + c4 + 3 < K) ? v.w : 0.f;
                    *(float4*)&e_lds[row * KC + c4] = o;
                }
            }
            // ---- stage W [KC][64] transposed + swizzled ----
            {
                const int passes = (64 * lpr) >> 8;
                for (int ps = 0; ps < passes; ++ps) {
                    const int idx = ps * 256 + tid;
                    const int rz  = idx / lpr;
                    const int c4  = (idx - rz * lpr) * 4;
                    const float4 v = *(const float4*)(weight + ((size_t)p * 256 + z0 + rz) * 256 + kbase + c4);
                    const float vv[4] = {v.x, v.y, v.z, v.w};
#pragma unroll
                    for (int j = 0; j < 4; ++j) {
                        const int kk = c4 + j;
                        w_lds[kk * 64 + ((rz + 4 * kk) & 63)] =
                            (kbase + kk < K) ? vv[j] : 0.f;
                    }
                }
            }
            __syncthreads();

            // ---- compute: KC/4 macro-steps, 8 ds_read_b128 + 64 FMA each ----
            const float* e0 = &e_lds[(tg * 4 + 0) * KC];
            const float* e1 = &e_lds[(tg * 4 + 1) * KC];
            const float* e2 = &e_lds[(tg * 4 + 2) * KC];
            const float* e3 = &e_lds[(tg * 4 + 3) * KC];
#pragma unroll 2
            for (int k = 0; k < KC; k += 4) {
                const float4 a0 = *(const float4*)(e0 + k);
                const float4 a1 = *(const float4*)(e1 + k);
                const float4 a2 = *(const float4*)(e2 + k);
                const float4 a3 = *(const float4*)(e3 + k);
                float4 w[4];
#pragma unroll
                for (int j = 0; j < 4; ++j)
                    w[j] = *(const float4*)&w_lds[(k + j) * 64 + ((zg4 + 4 * (k + j)) & 63)];
                const float ea[4][4] = {{a0.x,a0.y,a0.z,a0.w}, {a1.x,a1.y,a1.z,a1.w},
                                        {a2.x,a2.y,a2.z,a2.w}, {a3.x,a3.y,a3.z,a3.w}};
                const float wv[4][4] = {{w[0].x,w[0].y,w[0].z,w[0].w}, {w[1].x,w[1].y,w[1].z,w[1].w},
                                        {w[2].x,w[2].y,w[2].z,w[2].w}, {w[3].x,w[3].y,w[3].z,w[3].w}};
#pragma unroll
                for (int i = 0; i < 4; ++i)
#pragma unroll
                    for (int j = 0; j < 4; ++j) {
                        acc[i][0] = fmaf(ea[i][j], wv[j][0], acc[i][0]);
                        acc[i][1] = fmaf(ea[i][j], wv[j][1], acc[i][1]);
                        acc[i][2] = fmaf(ea[i][j], wv[j][2], acc[i][2]);
                        acc[i][3] = fmaf(ea[i][j], wv[j][3], acc[i][3]);
                    }
            }
            __syncthreads();
        }

        // ---- epilogue ----
#pragma unroll
        for (int i = 0; i < 4; ++i) {
            const int t = tg * 4 + i;
            if (t < ntile) {
                float4 o = {acc[i][0], acc[i][1], acc[i][2], acc[i][3]};
                *(float4*)(out + (size_t)oidx[t] * 256 + z0 + zg4) = o;
            }
        }
    }
}

// ---------- generic fallback ----------
__global__ void naive_k(const int* __restrict__ x, const float* __restrict__ emb,
                        const float* __restrict__ w, const int* __restrict__ parts,
                        float* __restrict__ out, int D, int P) {
    const int i = blockIdx.x;
    const int tokrow = x[i];
    const int p = parts[tokrow];
    const int K = D >> p;
    const float* er = emb + (size_t)tokrow * D;
    for (int z = threadIdx.x; z < D; z += blockDim.x) {
        const float* wr = w + ((size_t)p * D + z) * D;
        float acc = 0.f;
        for (int k = 0; k < K; ++k) acc = fmaf(er[k], wr[k], acc);
        out[(size_t)i * D + z] = acc;
    }
}

extern "C" void kernel_launch(void* const* d_in, const int* in_sizes, int n_in,
                              void* d_out, int out_size, void* d_ws, size_t ws_size,
                              hipStream_t stream) {
    const int*   xi    = (const int*)d_in[0];
    const float* emb   = (const float*)d_in[1];
    const float* wgt   = (const float*)d_in[2];
    const int*   parts = (const int*)d_in[3];
    float* out = (float*)d_out;

    const int NT = in_sizes[0];
    const long long V = in_sizes[3];
    const int D = (int)(in_sizes[1] / V);
    const int P = (int)(in_sizes[2] / ((long long)D * D));
    const size_t need = 32 + (size_t)P * (size_t)NT * sizeof(int);

    if (D == 256 && P == 8 && ws_size >= need) {
        int* counts  = (int*)d_ws;
        int* buckets = (int*)((char*)d_ws + 32);
        hipMemsetAsync(counts, 0, 32, stream);
        bucket_k<<<(NT + 255) / 256, 256, 0, stream>>>(xi, parts, counts, buckets, NT);
        dim3 grid(XB, 4, 8);
        // R5 PROBE: 5 idempotent launches; T_gemm = (total_us - 168.0) / 4.
        fge_gemm<<<grid, 256, 0, stream>>>(xi, emb, wgt, counts, buckets, out, NT);
        fge_gemm<<<grid, 256, 0, stream>>>(xi, emb, wgt, counts, buckets, out, NT);
        fge_gemm<<<grid, 256, 0, stream>>>(xi, emb, wgt, counts, buckets, out, NT);
        fge_gemm<<<grid, 256, 0, stream>>>(xi, emb, wgt, counts, buckets, out, NT);
        fge_gemm<<<grid, 256, 0, stream>>>(xi, emb, wgt, counts, buckets, out, NT);
    } else {
        naive_k<<<NT, 256, 0, stream>>>(xi, emb, wgt, parts, out, D, P);
    }
}

// Round 7
// 185.686 us; speedup vs baseline: 1.3883x; 1.3883x over previous
//
#include <hip/hip_runtime.h>

typedef unsigned short u16;
typedef unsigned int   u32;
typedef __attribute__((ext_vector_type(8))) __bf16 bf16x8;
typedef __attribute__((ext_vector_type(4))) float  f32x4;

// fp32 -> bf16 bits, round-to-nearest-even
__device__ __forceinline__ u16 f2bf(float f) {
    u32 u = __float_as_uint(f);
    return (u16)((u + 0x7FFFu + ((u >> 16) & 1u)) >> 16);
}

// ---------- kernel 1: bucket tokens by partition ----------
__global__ void bucket_k(const int* __restrict__ x, const int* __restrict__ parts,
                         int* __restrict__ counts, int* __restrict__ buckets, int NT) {
    __shared__ int lcount[8];
    __shared__ int lbase[8];
    const int tid = threadIdx.x;
    if (tid < 8) lcount[tid] = 0;
    __syncthreads();
    const int i = blockIdx.x * blockDim.x + tid;
    int p = 0, lpos = 0;
    const bool valid = (i < NT);
    if (valid) {
        p = parts[x[i]];
        lpos = atomicAdd(&lcount[p], 1);
    }
    __syncthreads();
    if (tid < 8)
        lbase[tid] = lcount[tid] ? atomicAdd(&counts[tid], lcount[tid]) : 0;
    __syncthreads();
    if (valid)
        buckets[(size_t)p * NT + lbase[p] + lpos] = i;
}

// ---------- kernel 2: grouped MFMA GEMM per partition ----------
// R6: bf16 MFMA (threshold 1.54 = 8*eps_bf16*scale budgets for bf16 inputs).
// Block = 64 tokens x 256 z; A=W (m=z), B=E (n=token) so C/D cols=token,
// rows=z -> float4 fp32 out stores. E fetched from HBM exactly once.
// LDS rows stride 72 u16 (144B): frag b128 reads 16B-aligned, 2-way banks (free).
#define TT 64
#define XB 40
#define SJ 72

__global__ __launch_bounds__(256)
void fge_mfma(const int* __restrict__ x,
              const float* __restrict__ emb,
              const float* __restrict__ weight,
              const int* __restrict__ counts,
              const int* __restrict__ buckets,
              float* __restrict__ out, int NT) {
    const int p = blockIdx.y;
    const int n = counts[p];
    if ((int)(blockIdx.x * TT) >= n) return;
    const int K   = 256 >> p;                  // true active dim
    const int KC  = (K >= 64) ? 64 : 32;       // chunk (p<=2: 64; p>=3: 32, K=16 zero-padded)
    const int nch = (K + KC - 1) / KC;         // 4,2,1,1,...
    const int shf = (KC == 64) ? 4 : 3;        // log2(float4 per row)
    const int lpr = 1 << shf;
    const int tid  = threadIdx.x;
    const int lane = tid & 63;
    const int wv   = tid >> 6;                 // wave id: owns z range wv*64..+63
    const int l15  = lane & 15;
    const int lq   = lane >> 4;                // 0..3

    __shared__ u16 w_lds[256 * SJ];            // [z][k] bf16, 36 KB
    __shared__ u16 e_lds[TT * SJ];             // [tok][k] bf16, 9 KB
    __shared__ int vrow[TT];
    __shared__ int oidx[TT];

    for (int t0 = blockIdx.x * TT; t0 < n; t0 += XB * TT) {
        const int ntile = min(TT, n - t0);
        __syncthreads();                       // protect prior iter's LDS
        if (tid < TT) {
            int idx = 0, row = 0;
            if (tid < ntile) {
                idx = buckets[(size_t)p * NT + t0 + tid];
                row = x[idx];
            }
            oidx[tid] = idx;
            vrow[tid] = row;                   // row 0 dummy for invalid slots
        }
        __syncthreads();

        f32x4 acc[4][4];
#pragma unroll
        for (int mi = 0; mi < 4; ++mi)
#pragma unroll
            for (int ni = 0; ni < 4; ++ni)
                acc[mi][ni] = (f32x4){0.f, 0.f, 0.f, 0.f};

        for (int ch = 0; ch < nch; ++ch) {
            const int kb = ch * KC;

            // ---- stage W [256][KC] fp32->bf16 (mask k>=K for K=16) ----
            for (int idx = tid; idx < (256 << shf); idx += 256) {
                const int rz = idx >> shf;
                const int c4 = (idx & (lpr - 1)) * 4;
                const float4 v = *(const float4*)(weight + ((size_t)p * 256 + rz) * 256 + kb + c4);
                ushort4 h;
                h.x = (kb + c4 + 0 < K) ? f2bf(v.x) : (u16)0;
                h.y = (kb + c4 + 1 < K) ? f2bf(v.y) : (u16)0;
                h.z = (kb + c4 + 2 < K) ? f2bf(v.z) : (u16)0;
                h.w = (kb + c4 + 3 < K) ? f2bf(v.w) : (u16)0;
                *(ushort4*)&w_lds[rz * SJ + c4] = h;
            }
            // ---- stage E [TT][KC] fp32->bf16 ----
            for (int idx = tid; idx < (TT << shf); idx += 256) {
                const int rt = idx >> shf;
                const int c4 = (idx & (lpr - 1)) * 4;
                const float4 v = *(const float4*)(emb + (size_t)vrow[rt] * 256 + kb + c4);
                ushort4 h;
                h.x = (kb + c4 + 0 < K) ? f2bf(v.x) : (u16)0;
                h.y = (kb + c4 + 1 < K) ? f2bf(v.y) : (u16)0;
                h.z = (kb + c4 + 2 < K) ? f2bf(v.z) : (u16)0;
                h.w = (kb + c4 + 3 < K) ? f2bf(v.w) : (u16)0;
                *(ushort4*)&e_lds[rt * SJ + c4] = h;
            }
            __syncthreads();

            // ---- MFMA: per k-step, 8 frag b128 loads + 16 mfma ----
            const int ksteps = KC >> 5;        // 2 or 1
            for (int ks = 0; ks < ksteps; ++ks) {
                const int ko = ks * 32 + lq * 8;
                bf16x8 a[4], b[4];
#pragma unroll
                for (int mi = 0; mi < 4; ++mi)
                    a[mi] = *(const bf16x8*)&w_lds[(wv * 64 + mi * 16 + l15) * SJ + ko];
#pragma unroll
                for (int ni = 0; ni < 4; ++ni)
                    b[ni] = *(const bf16x8*)&e_lds[(ni * 16 + l15) * SJ + ko];
#pragma unroll
                for (int mi = 0; mi < 4; ++mi)
#pragma unroll
                    for (int ni = 0; ni < 4; ++ni)
                        acc[mi][ni] = __builtin_amdgcn_mfma_f32_16x16x32_bf16(
                            a[mi], b[ni], acc[mi][ni], 0, 0, 0);
            }
            __syncthreads();                   // before next chunk overwrites LDS
        }

        // ---- epilogue: C/D col=token(l15), rows=z quad lq*4+reg -> float4 ----
#pragma unroll
        for (int ni = 0; ni < 4; ++ni) {
            const int t = ni * 16 + l15;
            if (t < ntile) {
                float* ob = out + (size_t)oidx[t] * 256;
#pragma unroll
                for (int mi = 0; mi < 4; ++mi) {
                    const int z = wv * 64 + mi * 16 + lq * 4;
                    float4 o = {acc[mi][ni].x, acc[mi][ni].y, acc[mi][ni].z, acc[mi][ni].w};
                    *(float4*)(ob + z) = o;
                }
            }
        }
    }
}

// ---------- generic fallback (any D/P, or ws too small) ----------
__global__ void naive_k(const int* __restrict__ x, const float* __restrict__ emb,
                        const float* __restrict__ w, const int* __restrict__ parts,
                        float* __restrict__ out, int D, int P) {
    const int i = blockIdx.x;
    const int tokrow = x[i];
    const int p = parts[tokrow];
    const int K = D >> p;
    const float* er = emb + (size_t)tokrow * D;
    for (int z = threadIdx.x; z < D; z += blockDim.x) {
        const float* wr = w + ((size_t)p * D + z) * D;
        float acc = 0.f;
        for (int k = 0; k < K; ++k) acc = fmaf(er[k], wr[k], acc);
        out[(size_t)i * D + z] = acc;
    }
}

extern "C" void kernel_launch(void* const* d_in, const int* in_sizes, int n_in,
                              void* d_out, int out_size, void* d_ws, size_t ws_size,
                              hipStream_t stream) {
    const int*   xi    = (const int*)d_in[0];
    const float* emb   = (const float*)d_in[1];
    const float* wgt   = (const float*)d_in[2];
    const int*   parts = (const int*)d_in[3];
    float* out = (float*)d_out;

    const int NT = in_sizes[0];
    const long long V = in_sizes[3];
    const int D = (int)(in_sizes[1] / V);
    const int P = (int)(in_sizes[2] / ((long long)D * D));
    const size_t need = 32 + (size_t)P * (size_t)NT * sizeof(int);

    if (D == 256 && P == 8 && ws_size >= need) {
        int* counts  = (int*)d_ws;
        int* buckets = (int*)((char*)d_ws + 32);
        hipMemsetAsync(counts, 0, 32, stream);
        bucket_k<<<(NT + 255) / 256, 256, 0, stream>>>(xi, parts, counts, buckets, NT);
        dim3 grid(XB, 8);
        fge_mfma<<<grid, 256, 0, stream>>>(xi, emb, wgt, counts, buckets, out, NT);
    } else {
        naive_k<<<NT, 256, 0, stream>>>(xi, emb, wgt, parts, out, D, P);
    }
}